// Round 1
// baseline (806.446 us; speedup 1.0000x reference)
//
#include <hip/hip_runtime.h>
#include <hip/hip_bf16.h>
#include <cstdint>

// Problem constants (fixed-shape problem)
constexpr int NT   = 8192;   // tokens
constexpr int TOPK = 2;
constexpr int H    = 1024;   // hidden (K of gemm0, N of gemm1)
constexpr int FFN  = 4096;   // ffn hidden (N of gemm0, K of gemm1)
constexpr int E    = 8;      // experts
constexpr int M    = NT * TOPK;   // 16384 dispatched rows
constexpr int CAP  = M / E;       // 2048 rows per expert

typedef unsigned short u16;
typedef short short8 __attribute__((ext_vector_type(8)));
typedef float f32x4 __attribute__((ext_vector_type(4)));

// ---------- helpers ----------
__device__ __forceinline__ u16 f2bf(float f) {
  union { float f; unsigned u; } c{f};
  unsigned r = (c.u + 0x7FFFu + ((c.u >> 16) & 1u)) >> 16;  // RNE
  return (u16)r;
}
__device__ __forceinline__ float bf2f(u16 u) {
  union { unsigned u; float f; } c{((unsigned)u) << 16};
  return c.f;
}
// async global->LDS direct copy, 16B per lane. LDS dest = wave-uniform base + lane*16.
__device__ __forceinline__ void async16(const void* g, void* l) {
  auto gp = reinterpret_cast<const __attribute__((address_space(1))) unsigned*>(
      reinterpret_cast<uintptr_t>(g));
  auto lp = reinterpret_cast<__attribute__((address_space(3))) unsigned*>(
      reinterpret_cast<uintptr_t>(l));
  __builtin_amdgcn_global_load_lds(gp, lp, 16, 0, 0);
}

// ---------- kernel 1: scatter + fp32->bf16 cast ----------
// one block per token; writes both topk replica rows of the dispatched buffer
__global__ void scatter_cast_kernel(const float* __restrict__ x,
                                    const int* __restrict__ sidx,
                                    u16* __restrict__ disp) {
  const int t = blockIdx.x;
  const int tid = threadIdx.x;          // 256 threads, 4 elems each
  const int r0 = sidx[2 * t + 0];
  const int r1 = sidx[2 * t + 1];
  float4 v = ((const float4*)(x + (size_t)t * H))[tid];
  ushort4 b;
  b.x = f2bf(v.x); b.y = f2bf(v.y); b.z = f2bf(v.z); b.w = f2bf(v.w);
  ((ushort4*)disp)[(size_t)r0 * (H / 4) + tid] = b;
  ((ushort4*)disp)[(size_t)r1 * (H / 4) + tid] = b;
}

// ---------- kernel 2: W [E][K][N] fp32 -> WT [E][N][K] bf16 ----------
__global__ void transpose_cvt_kernel(const float* __restrict__ W,
                                     u16* __restrict__ WT,
                                     int K, int N) {
  __shared__ float tile[32][33];
  const int e = blockIdx.z;
  const float* Wp = W + (size_t)e * K * N;
  u16* Tp = WT + (size_t)e * K * N;
  const int k0 = blockIdx.y * 32;
  const int n0 = blockIdx.x * 32;
  const int tx = threadIdx.x;  // 0..31
  const int ty = threadIdx.y;  // 0..7
#pragma unroll
  for (int i = 0; i < 32; i += 8)
    tile[ty + i][tx] = Wp[(size_t)(k0 + ty + i) * N + n0 + tx];
  __syncthreads();
#pragma unroll
  for (int i = 0; i < 32; i += 8)
    Tp[(size_t)(n0 + ty + i) * K + k0 + tx] = f2bf(tile[tx][ty + i]);
}

// ---------- m97-style bf16 GEMM: C[M,N] = A[M,K] * Bt[N,K]^T ----------
// 128x128 block tile, BK=32, 4 waves (2x2), each wave 4x4 of 16x16x32 MFMA.
template <bool GELU>
__global__ __launch_bounds__(256)
void gemm_bt_kernel(const u16* __restrict__ A,   // [E][Mn][Kn] bf16, row-major
                    const u16* __restrict__ Bt,  // [E][Nn][Kn] bf16, row-major
                    u16* __restrict__ C,         // [E][Mn][Nn] bf16
                    int Mn, int Nn, int Kn) {
  __shared__ __align__(16) u16 lA[128 * 32];   // [row][k] rows of 64B
  __shared__ __align__(16) u16 lB[128 * 32];   // [n][k]
  const int e  = blockIdx.z;
  const int m0 = blockIdx.y * 128;
  const int n0 = blockIdx.x * 128;
  const u16* Ae = A  + (size_t)e * Mn * Kn + (size_t)m0 * Kn;
  const u16* Be = Bt + (size_t)e * Nn * Kn + (size_t)n0 * Kn;
  u16* Ce = C + (size_t)e * Mn * Nn;

  const int tid  = threadIdx.x;
  const int lane = tid & 63;
  const int wave = tid >> 6;
  const int wr = wave >> 1, wc = wave & 1;   // 2x2 wave grid, 64x64 each
  const int lhi = lane >> 4, llo = lane & 15;

  f32x4 acc[4][4] = {};

  // staging map: instruction i covers tile rows [i*16, i*16+16); wave handles
  // insts {2w, 2w+1}; lane l -> row i*16 + l/4, 16B chunk (l&3) within 64B row
  const int srow0 = (wave * 2 + 0) * 16 + (lane >> 2);
  const int srow1 = (wave * 2 + 1) * 16 + (lane >> 2);
  const int skoff = (lane & 3) * 8;  // elements

  for (int kt = 0; kt < Kn; kt += 32) {
    async16(Ae + (size_t)srow0 * Kn + kt + skoff, &lA[(wave * 2 + 0) * 512]);
    async16(Ae + (size_t)srow1 * Kn + kt + skoff, &lA[(wave * 2 + 1) * 512]);
    async16(Be + (size_t)srow0 * Kn + kt + skoff, &lB[(wave * 2 + 0) * 512]);
    async16(Be + (size_t)srow1 * Kn + kt + skoff, &lB[(wave * 2 + 1) * 512]);
    __syncthreads();  // compiler drains vmcnt before barrier

    short8 af[4], bf[4];
#pragma unroll
    for (int i = 0; i < 4; ++i)
      af[i] = *(const short8*)&lA[(wr * 64 + i * 16 + llo) * 32 + lhi * 8];
#pragma unroll
    for (int j = 0; j < 4; ++j)
      bf[j] = *(const short8*)&lB[(wc * 64 + j * 16 + llo) * 32 + lhi * 8];
#pragma unroll
    for (int i = 0; i < 4; ++i)
#pragma unroll
      for (int j = 0; j < 4; ++j)
        acc[i][j] = __builtin_amdgcn_mfma_f32_16x16x32_bf16(af[i], bf[j], acc[i][j], 0, 0, 0);
    __syncthreads();  // protect LDS before next stage
  }

  // epilogue: C/D layout col=lane&15, row=(lane>>4)*4+reg  [m89-verified]
#pragma unroll
  for (int i = 0; i < 4; ++i) {
    const int mrow = m0 + wr * 64 + i * 16 + lhi * 4;
#pragma unroll
    for (int j = 0; j < 4; ++j) {
      const int ncol = n0 + wc * 64 + j * 16 + llo;
#pragma unroll
      for (int r = 0; r < 4; ++r) {
        float v = acc[i][j][r];
        if (GELU) v = 0.5f * v * (1.0f + erff(v * 0.70710678118654752f));
        Ce[(size_t)(mrow + r) * Nn + ncol] = f2bf(v);
      }
    }
  }
}

// ---------- kernel 4: gather + sum topk -> fp32 out ----------
__global__ void gather_sum_kernel(const u16* __restrict__ ye,
                                  const int* __restrict__ sidx,
                                  float* __restrict__ out) {
  const int t = blockIdx.x;
  const int tid = threadIdx.x;  // 256
  const int r0 = sidx[2 * t + 0];
  const int r1 = sidx[2 * t + 1];
  ushort4 a = ((const ushort4*)ye)[(size_t)r0 * (H / 4) + tid];
  ushort4 b = ((const ushort4*)ye)[(size_t)r1 * (H / 4) + tid];
  float4 s;
  s.x = bf2f(a.x) + bf2f(b.x);
  s.y = bf2f(a.y) + bf2f(b.y);
  s.z = bf2f(a.z) + bf2f(b.z);
  s.w = bf2f(a.w) + bf2f(b.w);
  ((float4*)out)[(size_t)t * (H / 4) + tid] = s;
}

extern "C" void kernel_launch(void* const* d_in, const int* in_sizes, int n_in,
                              void* d_out, int out_size, void* d_ws, size_t ws_size,
                              hipStream_t stream) {
  (void)in_sizes; (void)n_in; (void)out_size; (void)ws_size;
  const float* x    = (const float*)d_in[0];
  const float* w0   = (const float*)d_in[1];
  const float* w1   = (const float*)d_in[2];
  const int*   sidx = (const int*)d_in[3];
  float* out = (float*)d_out;

  // workspace layout (224 MiB total):
  //   wt  : shared W0^T / W1^T bf16 buffer   [E*FFN*H] = 64 Mi elems (67,108,864 B)
  //   disp: dispatched bf16 [M][H] (later aliased as ye)     (33,554,432 B)
  //   mid : gelu(x@W0) bf16 [E][CAP][FFN]                    (134,217,728 B)
  char* ws = (char*)d_ws;
  u16* wt   = (u16*)ws;
  u16* disp = (u16*)(ws + (size_t)E * FFN * H * 2);
  u16* mid  = (u16*)(ws + (size_t)E * FFN * H * 2 + (size_t)M * H * 2);
  u16* ye   = disp;  // disp dead after gemm0 -> reuse for gemm1 output

  // 1) scatter + cast
  scatter_cast_kernel<<<NT, 256, 0, stream>>>(x, sidx, disp);
  // 2) W0 [E][H][FFN] fp32 -> wt [E][FFN][H] bf16
  transpose_cvt_kernel<<<dim3(FFN / 32, H / 32, E), dim3(32, 8), 0, stream>>>(w0, wt, H, FFN);
  // 3) mid = gelu(disp @ W0)
  gemm_bt_kernel<true><<<dim3(FFN / 128, CAP / 128, E), 256, 0, stream>>>(
      disp, wt, mid, CAP, FFN, H);
  // 4) W1 [E][FFN][H] fp32 -> wt [E][H][FFN] bf16
  transpose_cvt_kernel<<<dim3(H / 32, FFN / 32, E), dim3(32, 8), 0, stream>>>(w1, wt, FFN, H);
  // 5) ye = mid @ W1
  gemm_bt_kernel<false><<<dim3(H / 128, CAP / 128, E), 256, 0, stream>>>(
      mid, wt, ye, CAP, H, FFN);
  // 6) out[t] = ye[s0] + ye[s1]
  gather_sum_kernel<<<NT, 256, 0, stream>>>(ye, sidx, out);
}

// Round 2
// 698.795 us; speedup vs baseline: 1.1541x; 1.1541x over previous
//
#include <hip/hip_runtime.h>
#include <hip/hip_bf16.h>
#include <cstdint>

// Problem constants (fixed-shape problem)
constexpr int NT   = 8192;   // tokens
constexpr int TOPK = 2;
constexpr int H    = 1024;   // hidden (K of gemm0, N of gemm1)
constexpr int FFN  = 4096;   // ffn hidden (N of gemm0, K of gemm1)
constexpr int E    = 8;      // experts
constexpr int M    = NT * TOPK;   // 16384 dispatched rows
constexpr int CAP  = M / E;       // 2048 rows per expert

typedef unsigned short u16;
typedef short short8 __attribute__((ext_vector_type(8)));
typedef float f32x4 __attribute__((ext_vector_type(4)));

// ---------- helpers ----------
__device__ __forceinline__ u16 f2bf(float f) {
  union { float f; unsigned u; } c{f};
  unsigned r = (c.u + 0x7FFFu + ((c.u >> 16) & 1u)) >> 16;  // RNE
  return (u16)r;
}
__device__ __forceinline__ float bf2f(u16 u) {
  union { unsigned u; float f; } c{((unsigned)u) << 16};
  return c.f;
}
// async global->LDS direct copy, 16B per lane. LDS dest = wave-uniform base + lane*16.
__device__ __forceinline__ void async16(const void* g, void* l) {
  auto gp = reinterpret_cast<const __attribute__((address_space(1))) unsigned*>(
      reinterpret_cast<uintptr_t>(g));
  auto lp = reinterpret_cast<__attribute__((address_space(3))) unsigned*>(
      reinterpret_cast<uintptr_t>(l));
  __builtin_amdgcn_global_load_lds(gp, lp, 16, 0, 0);
}

// ---------- kernel 1: scatter + fp32->bf16 cast ----------
__global__ void scatter_cast_kernel(const float* __restrict__ x,
                                    const int* __restrict__ sidx,
                                    u16* __restrict__ disp) {
  const int t = blockIdx.x;
  const int tid = threadIdx.x;          // 256 threads, 4 elems each
  const int r0 = sidx[2 * t + 0];
  const int r1 = sidx[2 * t + 1];
  float4 v = ((const float4*)(x + (size_t)t * H))[tid];
  ushort4 b;
  b.x = f2bf(v.x); b.y = f2bf(v.y); b.z = f2bf(v.z); b.w = f2bf(v.w);
  ((ushort4*)disp)[(size_t)r0 * (H / 4) + tid] = b;
  ((ushort4*)disp)[(size_t)r1 * (H / 4) + tid] = b;
}

// ---------- kernel 2 v2: W [E][K][N] fp32 -> WT [E][N][K] bf16, 64x64 tiles ----
// fp32 LDS tile stride 65: scalar writes bank = (kr+4u+j)&31 (free),
// scalar reads bank = (8c+j+n)&31 (2-way, free). 16B loads, 16B stores.
__global__ __launch_bounds__(256)
void transpose_cvt_kernel(const float* __restrict__ W,
                          u16* __restrict__ WT,
                          int K, int N) {
  __shared__ float tile[64][65];   // [k][n]
  const int e = blockIdx.z;
  const float* Wp = W + (size_t)e * K * N;
  u16* Tp = WT + (size_t)e * K * N;
  const int k0 = blockIdx.y * 64;
  const int n0 = blockIdx.x * 64;
  const int tid = threadIdx.x;

  // load: 4 passes, each covers 16 k-rows x 64 n (float4 per lane)
  const int u  = tid & 15;          // n-chunk within row
  const int krb = tid >> 4;         // 0..15
#pragma unroll
  for (int p = 0; p < 4; ++p) {
    const int kr = p * 16 + krb;
    float4 v = *(const float4*)&Wp[(size_t)(k0 + kr) * N + n0 + u * 4];
    tile[kr][u * 4 + 0] = v.x;
    tile[kr][u * 4 + 1] = v.y;
    tile[kr][u * 4 + 2] = v.z;
    tile[kr][u * 4 + 3] = v.w;
  }
  __syncthreads();

  // store: 2 passes; lane handles (n = tid/8, chunk c = tid%8 [+4 on pass 1])
  const int n  = tid >> 3;          // 0..31
  const int cb = tid & 7;           // chunk base selector
#pragma unroll
  for (int p = 0; p < 2; ++p) {
    const int nn = p * 32 + n;
    const int c  = cb;
    u16 pack[8];
#pragma unroll
    for (int j = 0; j < 8; ++j) pack[j] = f2bf(tile[c * 8 + j][nn]);
    *(short8*)&Tp[(size_t)(n0 + nn) * K + k0 + c * 8] = *(short8*)pack;
  }
}

// ---------- GEMM v2: C[M,N] = A[M,K] * Bt[N,K]^T, bf16 in/out ----------
// 128x128 tile, BK=64, XOR-swizzled LDS chunks (conflict-free frag reads),
// 1D grid: expert = b%8 (XCD pinning), 4x4 supertile order for L2 locality.
template <bool GELU>
__global__ __launch_bounds__(256)
void gemm_bt_kernel(const u16* __restrict__ A,   // [E][Mn][Kn] bf16 row-major
                    const u16* __restrict__ Bt,  // [E][Nn][Kn] bf16 row-major
                    u16* __restrict__ C,         // [E][Mn][Nn] bf16
                    int Mn, int Nn, int Kn, int nx, int ny) {
  __shared__ __align__(16) u16 lA[128 * 64];   // [row][64k], swizzled chunks
  __shared__ __align__(16) u16 lB[128 * 64];

  // block index -> (expert, m-tile, n-tile) with supertile swizzle
  const int b = blockIdx.x;
  const int e = b & 7;
  const int t = b >> 3;
  const int q = t & 15, s = t >> 4;
  const int sy = ny >> 2;                    // supertiles per column
  const int sm = s % sy, sn = s / sy;
  const int tm = sm * 4 + (q & 3), tn = sn * 4 + (q >> 2);
  const int m0 = tm * 128, n0 = tn * 128;
  (void)nx;

  const u16* Ae = A  + (size_t)e * Mn * Kn + (size_t)m0 * Kn;
  const u16* Be = Bt + (size_t)e * Nn * Kn + (size_t)n0 * Kn;
  u16* Ce = C + (size_t)e * Mn * Nn;

  const int tid  = threadIdx.x;
  const int lane = tid & 63;
  const int wave = tid >> 6;
  const int wr = wave >> 1, wc = wave & 1;   // 2x2 wave grid, 64x64 each
  const int lhi = lane >> 4, llo = lane & 15;

  // staging map: inst i covers rows [i*8, i*8+8); lane l -> row i*8 + l/8,
  // LDS chunk slot l%8; fetch global chunk (l%8)^(l/8) to realize the swizzle
  const int sr = lane >> 3;        // row-in-group 0..7
  const int gc = (lane & 7) ^ sr;  // swizzled global chunk 0..7

  f32x4 acc[4][4] = {};

  for (int kt = 0; kt < Kn; kt += 64) {
#pragma unroll
    for (int s2 = 0; s2 < 4; ++s2) {
      const int i = wave * 4 + s2;
      const int row = i * 8 + sr;
      async16(Ae + (size_t)row * Kn + kt + gc * 8, &lA[i * 512]);
      async16(Be + (size_t)row * Kn + kt + gc * 8, &lB[i * 512]);
    }
    __syncthreads();

#pragma unroll 1
    for (int ks = 0; ks < 2; ++ks) {
      short8 af[4], bf[4];
#pragma unroll
      for (int i = 0; i < 4; ++i) {
        const int row = wr * 64 + i * 16 + llo;
        const int pc = (ks * 4 + lhi) ^ (llo & 7);
        af[i] = *(const short8*)&lA[row * 64 + pc * 8];
      }
#pragma unroll
      for (int j = 0; j < 4; ++j) {
        const int row = wc * 64 + j * 16 + llo;
        const int pc = (ks * 4 + lhi) ^ (llo & 7);
        bf[j] = *(const short8*)&lB[row * 64 + pc * 8];
      }
#pragma unroll
      for (int i = 0; i < 4; ++i)
#pragma unroll
        for (int j = 0; j < 4; ++j)
          acc[i][j] = __builtin_amdgcn_mfma_f32_16x16x32_bf16(af[i], bf[j], acc[i][j], 0, 0, 0);
    }
    __syncthreads();
  }

  // epilogue: C/D layout col=lane&15, row=(lane>>4)*4+reg  [m89-verified]
#pragma unroll
  for (int i = 0; i < 4; ++i) {
    const int mrow = m0 + wr * 64 + i * 16 + lhi * 4;
#pragma unroll
    for (int j = 0; j < 4; ++j) {
      const int ncol = n0 + wc * 64 + j * 16 + llo;
#pragma unroll
      for (int r = 0; r < 4; ++r) {
        float v = acc[i][j][r];
        if (GELU) v = 0.5f * v * (1.0f + erff(v * 0.70710678118654752f));
        Ce[(size_t)(mrow + r) * Nn + ncol] = f2bf(v);
      }
    }
  }
}

// ---------- kernel 4: gather + sum topk -> fp32 out ----------
__global__ void gather_sum_kernel(const u16* __restrict__ ye,
                                  const int* __restrict__ sidx,
                                  float* __restrict__ out) {
  const int t = blockIdx.x;
  const int tid = threadIdx.x;  // 256
  const int r0 = sidx[2 * t + 0];
  const int r1 = sidx[2 * t + 1];
  ushort4 a = ((const ushort4*)ye)[(size_t)r0 * (H / 4) + tid];
  ushort4 b = ((const ushort4*)ye)[(size_t)r1 * (H / 4) + tid];
  float4 s;
  s.x = bf2f(a.x) + bf2f(b.x);
  s.y = bf2f(a.y) + bf2f(b.y);
  s.z = bf2f(a.z) + bf2f(b.z);
  s.w = bf2f(a.w) + bf2f(b.w);
  ((float4*)out)[(size_t)t * (H / 4) + tid] = s;
}

extern "C" void kernel_launch(void* const* d_in, const int* in_sizes, int n_in,
                              void* d_out, int out_size, void* d_ws, size_t ws_size,
                              hipStream_t stream) {
  (void)in_sizes; (void)n_in; (void)out_size; (void)ws_size;
  const float* x    = (const float*)d_in[0];
  const float* w0   = (const float*)d_in[1];
  const float* w1   = (const float*)d_in[2];
  const int*   sidx = (const int*)d_in[3];
  float* out = (float*)d_out;

  // workspace layout (224 MiB total):
  //   wt  : shared W0^T / W1^T bf16 buffer [E*FFN*H]   (67,108,864 B)
  //   disp: dispatched bf16 [M][H] (aliased as ye)     (33,554,432 B)
  //   mid : gelu(x@W0) bf16 [E][CAP][FFN]              (134,217,728 B)
  char* ws = (char*)d_ws;
  u16* wt   = (u16*)ws;
  u16* disp = (u16*)(ws + (size_t)E * FFN * H * 2);
  u16* mid  = (u16*)(ws + (size_t)E * FFN * H * 2 + (size_t)M * H * 2);
  u16* ye   = disp;  // disp dead after gemm0 -> reuse for gemm1 output

  // 1) scatter + cast
  scatter_cast_kernel<<<NT, 256, 0, stream>>>(x, sidx, disp);
  // 2) W0 [E][H][FFN] fp32 -> wt [E][FFN][H] bf16
  transpose_cvt_kernel<<<dim3(FFN / 64, H / 64, E), 256, 0, stream>>>(w0, wt, H, FFN);
  // 3) mid = gelu(disp @ W0): per-expert M=CAP,N=FFN,K=H; nx=32, ny=16
  gemm_bt_kernel<true><<<dim3((FFN / 128) * (CAP / 128) * E), 256, 0, stream>>>(
      disp, wt, mid, CAP, FFN, H, FFN / 128, CAP / 128);
  // 4) W1 [E][FFN][H] fp32 -> wt [E][H][FFN] bf16
  transpose_cvt_kernel<<<dim3(H / 64, FFN / 64, E), 256, 0, stream>>>(w1, wt, FFN, H);
  // 5) ye = mid @ W1: per-expert M=CAP,N=H,K=FFN; nx=8, ny=16
  gemm_bt_kernel<false><<<dim3((H / 128) * (CAP / 128) * E), 256, 0, stream>>>(
      mid, wt, ye, CAP, H, FFN, H / 128, CAP / 128);
  // 6) out[t] = ye[s0] + ye[s1]
  gather_sum_kernel<<<NT, 256, 0, stream>>>(ye, sidx, out);
}